// Round 1
// baseline (117.634 us; speedup 1.0000x reference)
//
#include <hip/hip_runtime.h>

typedef unsigned short u16;
typedef unsigned int u32;
typedef __attribute__((ext_vector_type(8))) short bf16x8;
typedef __attribute__((ext_vector_type(4))) float f32x4;

#define NUM_OPS 8
#define M_DIM 4096   // B*T
#define K_DIM 1024
#define N_DIM 1024
#define BK 64
#define KITERS (K_DIM / BK)   // 16
#define UNROLL _Pragma("unroll")

// Fragment-tiled operands: 1KB chunks = 16 rows x 32 k; slot l (16B) holds
// rows (l&15), k=(l>>4)*8+j  == exact MFMA A/B fragment lane order.

// ---- helpers ----------------------------------------------------------

__device__ __forceinline__ u16 f2b(float f) {
  union { float f; u32 u; } v; v.f = f;
  u32 r = v.u + 0x7fffu + ((v.u >> 16) & 1u);  // RNE
  return (u16)(r >> 16);
}

// packed f32x2 -> bf16x2 (RNE), single VALU instruction
__device__ __forceinline__ u32 cvtpk(float lo, float hi) {
  u32 r;
  asm("v_cvt_pk_bf16_f32 %0, %1, %2" : "=v"(r) : "v"(lo), "v"(hi));
  return r;
}

__device__ __forceinline__ int compute_idx(const float* __restrict__ logits,
                                           const float* __restrict__ u) {
  int best = 0; float bv = -3.4e38f;
UNROLL
  for (int i = 0; i < NUM_OPS; ++i) {
    float v = logits[i] - logf(-logf(u[i]));  // logits + gumbel
    if (v > bv) { bv = v; best = i; }
  }
  return best;
}

// async global->LDS, 16B/lane
__device__ __forceinline__ void gld_lds16(const void* g, void* l) {
  __builtin_amdgcn_global_load_lds(
      (__attribute__((address_space(1))) void*)(g),
      (__attribute__((address_space(3))) void*)(unsigned)(unsigned long long)(l),
      16, 0, 0);
}

// ---- prep: W[idx] -> wt (frag-tiled bf16) only; x handled in-GEMM ------
__global__ void prep_kernel(const float* __restrict__ W,
                            const float* __restrict__ logits,
                            const float* __restrict__ u,
                            u16* __restrict__ wt) {
  __shared__ u16 t[64][66];  // [k][n], +2 pad
  const int tid = threadIdx.x;
  const int wb = blockIdx.x;              // [0,256)
  const int kt = wb >> 4, nt = wb & 15;   // 64x64 tile of W[k][n]
  const int idx = compute_idx(logits, u);
  const float* Wi = W + (size_t)idx * K_DIM * N_DIM;
UNROLL
  for (int it = 0; it < 16; ++it) {
    int i = it * 256 + tid;
    int r = i >> 6, c = i & 63;
    t[r][c] = f2b(Wi[(size_t)(kt * 64 + r) * N_DIM + nt * 64 + c]);
  }
  __syncthreads();
UNROLL
  for (int it = 0; it < 2; ++it) {
    int s = it * 256 + tid;
    int c = s >> 6, l = s & 63;
    int ntl = c & 3, ktl = c >> 2;
    int kb = ktl * 32 + (l >> 4) * 8, nn = ntl * 16 + (l & 15);
    uint4 p;
    p.x = (u32)t[kb + 0][nn] | ((u32)t[kb + 1][nn] << 16);
    p.y = (u32)t[kb + 2][nn] | ((u32)t[kb + 3][nn] << 16);
    p.z = (u32)t[kb + 4][nn] | ((u32)t[kb + 5][nn] << 16);
    p.w = (u32)t[kb + 6][nn] | ((u32)t[kb + 7][nn] << 16);
    int chunk = (nt * 4 + ntl) * 32 + (kt * 2 + ktl);
    *(uint4*)(wt + (size_t)chunk * 512 + l * 8) = p;
  }
}

// ---- GEMM: out = x * W[idx] + b[idx] -----------------------------------
// BM=64, BN=128, BK=64; 256 thr = 4 waves (2m x 2n), wave tile 32x64.
// A staged from x (f32) via regs: load 1 iter ahead, cvt_pk->bf16, ds_write
// into the same frag-tiled LDS layout. B staged via gld_lds from wt.
// Grid 512 = 2 blocks/CU; dbuf; one barrier per K-iter.
__global__ __launch_bounds__(256) void gemm_kernel(
    const float* __restrict__ x, const u16* __restrict__ wt,
    const float* __restrict__ bvec, const float* __restrict__ logits,
    const float* __restrict__ u, float* __restrict__ out) {
  // unified chunk store: A chunks 0..7, B chunks 8..23 (24 KB per buf)
  __shared__ u16 sm[2][24 * 512];

  const int tid = threadIdx.x;
  const int w = tid >> 6, L = tid & 63;
  const int bid = blockIdx.x;
  const int mb = (bid & 7) * 8 + (bid >> 6);   // [0,64): XCD-local m-slabs
  const int nb = (bid >> 3) & 7;               // [0,8)

  // A staging: thread handles slots tid and tid+256 (chunks 0..3, 4..7)
  const float* asrc[2];
  int alofs[2];
UNROLL
  for (int j = 0; j < 2; ++j) {
    int s = tid + j * 256;
    int chunk = s >> 6, l = s & 63;
    asrc[j] = x + (size_t)(mb * 64 + (chunk >> 1) * 16 + (l & 15)) * K_DIM
                + (chunk & 1) * 32 + (l >> 4) * 8;
    alofs[j] = chunk * 512 + l * 8;
  }

  // B staging: wave w handles items 4w..4w+3 via gld_lds
  const u16* bsrc[4];
  int blofs[4];
UNROLL
  for (int j = 0; j < 4; ++j) {
    int item = 4 * w + j;
    int nt = item >> 1, dk = item & 1;
    bsrc[j] = wt + ((size_t)((nb * 8 + nt) * 32 + dk)) * 512 + L * 8;
    blofs[j] = (8 + item) * 512 + L * 8;
  }

  const int wm = w & 1, wn = w >> 1;
  int aoff[2][2], boff[4][2];
UNROLL
  for (int f = 0; f < 2; ++f)
UNROLL
    for (int dk = 0; dk < 2; ++dk)
      aoff[f][dk] = ((2 * wm + f) * 2 + dk) * 512 + L * 8;
UNROLL
  for (int t = 0; t < 4; ++t)
UNROLL
    for (int dk = 0; dk < 2; ++dk)
      boff[t][dk] = (8 + (4 * wn + t) * 2 + dk) * 512 + L * 8;

  f32x4 acc[2][4] = {};
  float4 gA[2][2], gB[2][2];

#define LOAD_A(dst, kk) do {                                          \
  UNROLL                                                              \
  for (int j_ = 0; j_ < 2; ++j_) {                                    \
    dst[j_][0] = *(const float4*)(asrc[j_] + (kk) * BK);              \
    dst[j_][1] = *(const float4*)(asrc[j_] + (kk) * BK + 4);          \
  } } while (0)

#define WRITE_A(src, bufi) do {                                       \
  UNROLL                                                              \
  for (int j_ = 0; j_ < 2; ++j_) {                                    \
    uint4 p_;                                                         \
    p_.x = cvtpk(src[j_][0].x, src[j_][0].y);                         \
    p_.y = cvtpk(src[j_][0].z, src[j_][0].w);                         \
    p_.z = cvtpk(src[j_][1].x, src[j_][1].y);                         \
    p_.w = cvtpk(src[j_][1].z, src[j_][1].w);                         \
    *(uint4*)(&sm[bufi][alofs[j_]]) = p_;                             \
  } } while (0)

#define STAGE_B(kk, bufi) do {                                        \
  const int ko_ = (kk) * 1024;                                        \
  UNROLL                                                              \
  for (int j_ = 0; j_ < 4; ++j_)                                      \
    gld_lds16(bsrc[j_] + ko_, &sm[bufi][blofs[j_]]);                  \
  } while (0)

#define COMPUTE(cur) do {                                             \
  bf16x8 af_[2][2], bf_[4][2];                                        \
  UNROLL                                                              \
  for (int f_ = 0; f_ < 2; ++f_)                                      \
    UNROLL                                                            \
    for (int dk_ = 0; dk_ < 2; ++dk_)                                 \
      af_[f_][dk_] = *(const bf16x8*)(&sm[cur][aoff[f_][dk_]]);       \
  UNROLL                                                              \
  for (int t_ = 0; t_ < 4; ++t_)                                      \
    UNROLL                                                            \
    for (int dk_ = 0; dk_ < 2; ++dk_)                                 \
      bf_[t_][dk_] = *(const bf16x8*)(&sm[cur][boff[t_][dk_]]);       \
  UNROLL                                                              \
  for (int dk_ = 0; dk_ < 2; ++dk_)                                   \
    UNROLL                                                            \
    for (int f_ = 0; f_ < 2; ++f_)                                    \
      UNROLL                                                          \
      for (int t_ = 0; t_ < 4; ++t_)                                  \
        acc[f_][t_] = __builtin_amdgcn_mfma_f32_16x16x32_bf16(        \
            af_[f_][dk_], bf_[t_][dk_], acc[f_][t_], 0, 0, 0);        \
  } while (0)

  // prologue: A0 -> buf0 (regs->cvt->LDS), B0 -> buf0, A1 in flight
  LOAD_A(gA, 0);
  STAGE_B(0, 0);
  WRITE_A(gA, 0);
  LOAD_A(gB, 1);

  for (int kk = 0; kk < KITERS; kk += 2) {
    __syncthreads();  // buf0 ready (B landed via vmcnt drain, A writes visible)
    if (kk + 1 < KITERS) { STAGE_B(kk + 1, 1); WRITE_A(gB, 1); }
    if (kk + 2 < KITERS) LOAD_A(gA, kk + 2);
    COMPUTE(0);

    __syncthreads();  // buf1 ready
    if (kk + 2 < KITERS) { STAGE_B(kk + 2, 0); WRITE_A(gA, 0); }
    if (kk + 3 < KITERS) LOAD_A(gB, kk + 3);
    COMPUTE(1);
  }

  // epilogue: C/D layout col=lane&15, row=(lane>>4)*4+reg
  const int idx = compute_idx(logits, u);
  const float* bi = bvec + (size_t)idx * N_DIM;
UNROLL
  for (int f = 0; f < 2; ++f) {
    int row = mb * 64 + 32 * wm + 16 * f + (L >> 4) * 4;
UNROLL
    for (int t = 0; t < 4; ++t) {
      int col = nb * 128 + 64 * wn + 16 * t + (L & 15);
      float bv = bi[col];
UNROLL
      for (int r = 0; r < 4; ++r)
        out[(size_t)(row + r) * N_DIM + col] = acc[f][t][r] + bv;
    }
  }
}

// ---- launch -----------------------------------------------------------

extern "C" void kernel_launch(void* const* d_in, const int* in_sizes, int n_in,
                              void* d_out, int out_size, void* d_ws, size_t ws_size,
                              hipStream_t stream) {
  const float* x      = (const float*)d_in[0];
  const float* W      = (const float*)d_in[1];
  const float* bvec   = (const float*)d_in[2];
  const float* logits = (const float*)d_in[3];
  const float* u      = (const float*)d_in[4];
  float* out = (float*)d_out;

  u16* wt = (u16*)d_ws;  // frag-tiled W[idx], 2 MB

  prep_kernel<<<256, 256, 0, stream>>>(W, logits, u, wt);
  gemm_kernel<<<512, 256, 0, stream>>>(x, wt, bvec, logits, u, out);
}

// Round 2
// 109.871 us; speedup vs baseline: 1.0706x; 1.0706x over previous
//
#include <hip/hip_runtime.h>

typedef unsigned short u16;
typedef unsigned int u32;
typedef __attribute__((ext_vector_type(8))) short bf16x8;
typedef __attribute__((ext_vector_type(4))) float f32x4;

#define NUM_OPS 8
#define M_DIM 4096   // B*T
#define K_DIM 1024
#define N_DIM 1024
#define KITERS 16    // K / 64
#define UNROLL _Pragma("unroll")

// Fragment-tiled operands: 1KB chunks = 16 rows x 32 k; slot l (16B) holds
// rows (l&15), k=(l>>4)*8+j  == exact MFMA A/B fragment lane order.
// chunk index = rowtile*32 + ktile (ktile of 32 k).

// ---- helpers ----------------------------------------------------------

__device__ __forceinline__ u16 f2b(float f) {
  union { float f; u32 u; } v; v.f = f;
  u32 r = v.u + 0x7fffu + ((v.u >> 16) & 1u);  // RNE
  return (u16)(r >> 16);
}

__device__ __forceinline__ u32 pk2(float a, float b) {  // bf16(a) | bf16(b)<<16
  return (u32)f2b(a) | ((u32)f2b(b) << 16);
}

__device__ __forceinline__ int compute_idx(const float* __restrict__ logits,
                                           const float* __restrict__ u) {
  int best = 0; float bv = -3.4e38f;
UNROLL
  for (int i = 0; i < NUM_OPS; ++i) {
    float v = logits[i] - logf(-logf(u[i]));  // logits + gumbel
    if (v > bv) { bv = v; best = i; }
  }
  return best;
}

// ---- prep: x -> xb (frag-tiled bf16), W[idx] -> wt (frag-tiled bf16) ----
// (identical to the verified round-0 version)
__global__ void prep_kernel(const float* __restrict__ x, const float* __restrict__ W,
                            const float* __restrict__ logits, const float* __restrict__ u,
                            u16* __restrict__ xb, u16* __restrict__ wt) {
  const int tid = threadIdx.x;
  const int bid = blockIdx.x;
  if (bid < 2048) {
    const int chunk = bid * 4 + (tid >> 6), l = tid & 63;
    const int mtile = chunk >> 5, ktile = chunk & 31;
    const float* src = x + (size_t)(mtile * 16 + (l & 15)) * K_DIM
                         + ktile * 32 + (l >> 4) * 8;
    float4 f0 = *(const float4*)(src);
    float4 f1 = *(const float4*)(src + 4);
    uint4 p;
    p.x = pk2(f0.x, f0.y); p.y = pk2(f0.z, f0.w);
    p.z = pk2(f1.x, f1.y); p.w = pk2(f1.z, f1.w);
    *(uint4*)(xb + (size_t)chunk * 512 + l * 8) = p;
  } else {
    __shared__ u16 t[64][66];  // [k][n], +2 pad
    const int wb = bid - 2048;
    const int kt = wb >> 4, nt = wb & 15;   // 64x64 tile of W[k][n]
    const int idx = compute_idx(logits, u);
    const float* Wi = W + (size_t)idx * K_DIM * N_DIM;
UNROLL
    for (int it = 0; it < 16; ++it) {
      int i = it * 256 + tid;
      int r = i >> 6, c = i & 63;
      t[r][c] = f2b(Wi[(size_t)(kt * 64 + r) * N_DIM + nt * 64 + c]);
    }
    __syncthreads();
UNROLL
    for (int it = 0; it < 2; ++it) {
      int s = it * 256 + tid;
      int c = s >> 6, l = s & 63;
      int ntl = c & 3, ktl = c >> 2;
      int kb = ktl * 32 + (l >> 4) * 8, nn = ntl * 16 + (l & 15);
      uint4 p;
      p.x = (u32)t[kb + 0][nn] | ((u32)t[kb + 1][nn] << 16);
      p.y = (u32)t[kb + 2][nn] | ((u32)t[kb + 3][nn] << 16);
      p.z = (u32)t[kb + 4][nn] | ((u32)t[kb + 5][nn] << 16);
      p.w = (u32)t[kb + 6][nn] | ((u32)t[kb + 7][nn] << 16);
      int chunk = (nt * 4 + ntl) * 32 + (kt * 2 + ktl);
      *(uint4*)(wt + (size_t)chunk * 512 + l * 8) = p;
    }
  }
}

// ---- GEMM: out = x * W[idx] + b[idx] -----------------------------------
// LDS-FREE, BARRIER-FREE. BM=64, BN=128; 4 waves (2m x 2n), wave tile 32x64.
// Operands are frag-tiled in workspace: a wave's fragment = contiguous 1KB
// chunk = one coalesced global_load_dwordx4 per lane, L2-resident (xb slab
// 1MB/XCD, wt 2MB, via XCD-aware bid swizzle). Each wave streams fragments
// global->VGPR->MFMA with a 2-deep register pipeline (named sets a0/b0,
// a1/b1 -> all static indexing, no scratch). No __syncthreads anywhere:
// no vmcnt(0) barrier drains; latency hidden by 2-deep ILP + 2 waves/SIMD.
__global__ __launch_bounds__(256) void gemm_kernel(
    const u16* __restrict__ xb, const u16* __restrict__ wt,
    const float* __restrict__ bvec, const float* __restrict__ logits,
    const float* __restrict__ u, float* __restrict__ out) {
  const int tid = threadIdx.x;
  const int w = tid >> 6, L = tid & 63;
  const int bid = blockIdx.x;
  const int mb = (bid & 7) * 8 + (bid >> 6);   // [0,64): XCD-local m-slabs
  const int nb = (bid >> 3) & 7;               // [0,8)
  const int wm = w & 1, wn = w >> 1;

  // per-wave fragment base pointers; frag (f,dk) at k-iter kk lives at
  //   abase + (f*32 + kk*2 + dk)*512   (elements; chunk = 512 u16 = 1KB)
  const u16* abase = xb + (size_t)((mb * 4 + 2 * wm) * 32) * 512 + L * 8;
  const u16* bbase = wt + (size_t)((nb * 8 + wn * 4) * 32) * 512 + L * 8;

  f32x4 acc[2][4] = {};
  bf16x8 a0[2][2], b0[4][2], a1[2][2], b1[4][2];

#define LOADF(A, B, kk) do {                                              \
  UNROLL                                                                  \
  for (int f_ = 0; f_ < 2; ++f_)                                          \
    UNROLL                                                                \
    for (int d_ = 0; d_ < 2; ++d_)                                        \
      A[f_][d_] = *(const bf16x8*)(abase + (f_ * 32 + (kk) * 2 + d_) * 512); \
  UNROLL                                                                  \
  for (int t_ = 0; t_ < 4; ++t_)                                          \
    UNROLL                                                                \
    for (int d_ = 0; d_ < 2; ++d_)                                        \
      B[t_][d_] = *(const bf16x8*)(bbase + (t_ * 32 + (kk) * 2 + d_) * 512); \
} while (0)

#define MFMAS(A, B) do {                                                  \
  UNROLL                                                                  \
  for (int d_ = 0; d_ < 2; ++d_)                                          \
    UNROLL                                                                \
    for (int f_ = 0; f_ < 2; ++f_)                                        \
      UNROLL                                                              \
      for (int t_ = 0; t_ < 4; ++t_)                                      \
        acc[f_][t_] = __builtin_amdgcn_mfma_f32_16x16x32_bf16(            \
            A[f_][d_], B[t_][d_], acc[f_][t_], 0, 0, 0);                  \
} while (0)

  // 2-deep prologue
  LOADF(a0, b0, 0);
  LOADF(a1, b1, 1);

UNROLL
  for (int kk = 0; kk < KITERS; kk += 2) {
    MFMAS(a0, b0);
    if (kk + 2 < KITERS) LOADF(a0, b0, kk + 2);
    MFMAS(a1, b1);
    if (kk + 3 < KITERS) LOADF(a1, b1, kk + 3);
  }

  // epilogue: C/D layout col=lane&15, row=(lane>>4)*4+reg
  const int idx = compute_idx(logits, u);
  const float* bi = bvec + (size_t)idx * N_DIM;
UNROLL
  for (int f = 0; f < 2; ++f) {
    int row = mb * 64 + 32 * wm + 16 * f + (L >> 4) * 4;
UNROLL
    for (int t = 0; t < 4; ++t) {
      int col = nb * 128 + 64 * wn + 16 * t + (L & 15);
      float bv = bi[col];
UNROLL
      for (int r = 0; r < 4; ++r)
        out[(size_t)(row + r) * N_DIM + col] = acc[f][t][r] + bv;
    }
  }
}

// ---- launch -----------------------------------------------------------

extern "C" void kernel_launch(void* const* d_in, const int* in_sizes, int n_in,
                              void* d_out, int out_size, void* d_ws, size_t ws_size,
                              hipStream_t stream) {
  const float* x      = (const float*)d_in[0];
  const float* W      = (const float*)d_in[1];
  const float* bvec   = (const float*)d_in[2];
  const float* logits = (const float*)d_in[3];
  const float* u      = (const float*)d_in[4];
  float* out = (float*)d_out;

  u16* xb = (u16*)d_ws;                          // frag-tiled x, 8 MB
  u16* wt = (u16*)d_ws + (size_t)M_DIM * K_DIM;  // frag-tiled W[idx], 2 MB

  prep_kernel<<<2048 + 256, 256, 0, stream>>>(x, W, logits, u, xb, wt);
  gemm_kernel<<<512, 256, 0, stream>>>(xb, wt, bvec, logits, u, out);
}